// Round 1
// baseline (412.366 us; speedup 1.0000x reference)
//
#include <hip/hip_runtime.h>
#include <math.h>

#define WIN   400
#define NREF  64
#define KTOP  8
#define NSNP  400000
#define NB    2
#define NA    3
#define NW    1000   // NSNP / WIN

// One block per (a, w): 4 waves, each wave handles 16 of the 64 ref rows.
// ref window tile = 64 rows x 400 f32, read once, used for both batch rows.
__global__ __launch_bounds__(256, 4) void topk_window_kernel(
    const float* __restrict__ mixed,    // [NB, NSNP]
    const float* __restrict__ ref,      // [NA, NREF, NSNP]
    const float* __restrict__ weights,  // [KTOP, 1]
    float* __restrict__ out)            // [NB*NA*NW] then [NB*NA*NW*KTOP] idx-as-float
{
    __shared__ float smix[NB][WIN];       // 3.2 KB
    __shared__ float winvals[NB][NREF];   // 512 B

    const int bid  = blockIdx.x;
    const int a    = bid / NW;
    const int w    = bid % NW;
    const int tid  = threadIdx.x;
    const int lane = tid & 63;
    const int wave = tid >> 6;

    // ---- stage mixed windows (2 x 400 floats = 200 float4) ----
    if (tid < NB * (WIN / 4)) {
        const int b  = tid / (WIN / 4);
        const int j4 = tid % (WIN / 4);
        const float4 v =
            reinterpret_cast<const float4*>(mixed + (size_t)b * NSNP + (size_t)w * WIN)[j4];
        reinterpret_cast<float4*>(&smix[b][0])[j4] = v;
    }
    __syncthreads();

    // ---- windowed dot products: row r, both batches ----
    const float4* m0p = reinterpret_cast<const float4*>(&smix[0][0]);
    const float4* m1p = reinterpret_cast<const float4*>(&smix[1][0]);
    for (int r = wave; r < NREF; r += 4) {
        const float4* row = reinterpret_cast<const float4*>(
            ref + (size_t)(a * NREF + r) * NSNP + (size_t)w * WIN);
        // 100 float4 per row: lane covers {lane, lane+64 (if <100)}
        float4 rv = row[lane];
        float4 m0 = m0p[lane];
        float4 m1 = m1p[lane];
        float acc0 = rv.x * m0.x + rv.y * m0.y + rv.z * m0.z + rv.w * m0.w;
        float acc1 = rv.x * m1.x + rv.y * m1.y + rv.z * m1.z + rv.w * m1.w;
        if (lane < (WIN / 4) - 64) {   // lanes 0..35
            float4 rv2 = row[lane + 64];
            float4 n0  = m0p[lane + 64];
            float4 n1  = m1p[lane + 64];
            acc0 += rv2.x * n0.x + rv2.y * n0.y + rv2.z * n0.z + rv2.w * n0.w;
            acc1 += rv2.x * n1.x + rv2.y * n1.y + rv2.z * n1.z + rv2.w * n1.w;
        }
        #pragma unroll
        for (int off = 32; off > 0; off >>= 1) {
            acc0 += __shfl_xor(acc0, off, 64);
            acc1 += __shfl_xor(acc1, off, 64);
        }
        if (lane == 0) {
            winvals[0][r] = acc0 * (1.0f / WIN);
            winvals[1][r] = acc1 * (1.0f / WIN);
        }
    }
    __syncthreads();

    // ---- top-8 over 64 refs (lane = ref index), jax.lax.top_k semantics ----
    if (wave < NB) {
        const int b  = wave;
        float myval  = winvals[b][lane];
        float wsum   = 0.0f;
        float idxs[KTOP];
        #pragma unroll
        for (int k = 0; k < KTOP; ++k) {
            float v = myval;
            int   i = lane;
            #pragma unroll
            for (int off = 32; off > 0; off >>= 1) {
                float v2 = __shfl_xor(v, off, 64);
                int   i2 = __shfl_xor(i, off, 64);
                if (v2 > v || (v2 == v && i2 < i)) { v = v2; i = i2; }
            }
            wsum   += weights[k] * v;       // weights is [K,1] -> weights[k]
            idxs[k] = (float)i;
            if (lane == i) myval = -INFINITY;  // remove winner, keep stability
        }
        if (lane == 0) {
            const int ow = (b * NA + a) * NW + w;
            out[ow] = wsum;
            float4* op = reinterpret_cast<float4*>(out + (size_t)NB * NA * NW + (size_t)ow * KTOP);
            op[0] = make_float4(idxs[0], idxs[1], idxs[2], idxs[3]);
            op[1] = make_float4(idxs[4], idxs[5], idxs[6], idxs[7]);
        }
    }
}

extern "C" void kernel_launch(void* const* d_in, const int* in_sizes, int n_in,
                              void* d_out, int out_size, void* d_ws, size_t ws_size,
                              hipStream_t stream) {
    const float* mixed   = (const float*)d_in[0];
    const float* ref     = (const float*)d_in[1];
    const float* weights = (const float*)d_in[2];
    float* out = (float*)d_out;
    topk_window_kernel<<<NA * NW, 256, 0, stream>>>(mixed, ref, weights, out);
}